// Round 8
// baseline (158.950 us; speedup 1.0000x reference)
//
#include <hip/hip_runtime.h>
#include <math.h>

#define CC 1024
#define SS 16
#define DD 512
#define RR (CC*SS)
#define EPSV 1e-8f
#define LDB 520    // B-tile row stride (shorts): bank-floor b128 reads
#define LDX 516    // phase-1 LDS row stride (floats): de-conflict strided reads
#define CHUNK 32   // B cols per double-buffer half
#define NCHUNK 16  // 512 cols per col-split / 32

typedef __attribute__((ext_vector_type(8))) short short8;
typedef __attribute__((ext_vector_type(4))) float f32x4;
typedef unsigned short ushort_t;

__device__ __forceinline__ unsigned short f2bf(float f) {
  unsigned u = __float_as_uint(f);
  u += 0x7fffu + ((u >> 16) & 1u);  // RNE
  return (unsigned short)(u >> 16);
}

__device__ __forceinline__ void async16(void* l, const void* g) {
  __builtin_amdgcn_global_load_lds(
      (const __attribute__((address_space(1))) void*)g,
      (__attribute__((address_space(3))) void*)l, 16, 0, 0);
}

__device__ __forceinline__ float softplusf(float v) {
  return (v > 20.f) ? v : log1pf(expf(v));
}

#define SBAR()   __builtin_amdgcn_s_barrier()
#define SCHED0() __builtin_amdgcn_sched_barrier(0)

// ================= fused persistent kernel =================
// Grid 256 x 256 threads, 1 block/CU (88KB LDS forces exclusivity; grid ==
// CU count -> all blocks co-resident -> sw grid barrier is deadlock-free).
// Phase 1: block (p,cb) computes stats for classes p*8..p*8+7 (k_pre math,
//   unchanged) and builds its waves' A-fragments IN REGISTERS (xn never
//   materialized). cb==0 sibling writes mn/simpos.
// Barrier: release-fence + atomic arrive + spin + acquire-fence.
// Phase 2: R7 k_gemm main loop (counted-vmcnt dbuf staging of mn tiles).
__global__ __launch_bounds__(256, 1) void k_fused(
    const float* __restrict__ x, ushort_t* __restrict__ mn,
    float* __restrict__ simpos, const float* __restrict__ wptr,
    const float* __restrict__ bptr, float* __restrict__ ps,
    unsigned* __restrict__ cnt) {
  __shared__ char smem[88064];     // 86 KB union -> 1 block/CU
  __shared__ float sums[DD];
  __shared__ float red[4];
  __shared__ float snm;
  __shared__ float rinv[SS];
  __shared__ float spos[SS];

  const int tid = threadIdx.x;
  const int wid = tid >> 6, lane = tid & 63;
  const int cL = lane & 15, quad = lane >> 4;
  const int bid = (int)blockIdx.x;
  const int p = bid >> 1, cb = bid & 1;
  const int r0 = p * 128, cbase = cb * 512;
  const int row0w = r0 + wid * 32;
  const float wp = softplusf(wptr[0]), bv = bptr[0];

  float* xs0 = (float*)smem;             // 2 x SS*LDX floats = 66048 B
  float* xs1 = (float*)smem + SS * LDX;

  short8 af[2][16];
  int jw[2];
  float sp[2][4], sacc[2][4];
#pragma unroll
  for (int rt = 0; rt < 2; ++rt) {
    jw[rt] = p * 8 + 2 * wid + rt;
#pragma unroll
    for (int r4 = 0; r4 < 4; ++r4) sacc[rt][r4] = 0.f;
  }

  // ---- phase 1: 8 classes, double-buffered async16 staging ----
  auto stage1 = [&](int r, float* dstb) {
    const float* src = x + (size_t)(p * 8 + r) * SS * DD;
#pragma unroll
    for (int t = 0; t < 8; ++t) {
      const int u0 = wid * 64 + t * 256;       // 64 contiguous float4 units
      const int row = u0 >> 7, d4 = u0 & 127;  // wave-uniform row/base
      async16(&dstb[row * LDX + d4 * 4 + lane * 4],
              src + (size_t)row * DD + d4 * 4 + lane * 4);
    }
  };

  stage1(0, xs0);
  for (int r = 0; r < 8; ++r) {
    float* xb = (r & 1) ? xs1 : xs0;
    if (r < 7) {
      stage1(r + 1, (r & 1) ? xs0 : xs1);
      SCHED0();
      asm volatile("s_waitcnt vmcnt(8)" ::: "memory");
    } else {
      asm volatile("s_waitcnt vmcnt(0)" ::: "memory");
    }
    SCHED0();
    __syncthreads();   // round-r data landed; prior readers done

    const int jc = p * 8 + r;
    // column sums (thread owns a float2 column pair)
    float sx = 0.f, sy = 0.f;
#pragma unroll
    for (int i = 0; i < SS; ++i) {
      float2 v = *(const float2*)(xb + i * LDX + tid * 2);
      sx += v.x; sy += v.y;
    }
    ((float2*)sums)[tid] = make_float2(sx, sy);
    const float mxs = sx * (1.0f / SS), mys = sy * (1.0f / SS);
    float m2 = mxs * mxs + mys * mys;
#pragma unroll
    for (int off = 32; off > 0; off >>= 1) m2 += __shfl_xor(m2, off, 64);
    if (lane == 0) red[wid] = m2;
    __syncthreads();
    if (tid == 0) snm = sqrtf(red[0] + red[1] + red[2] + red[3]);
    __syncthreads();
    if (cb == 0) {
      const float inm = (1.0f / SS) / snm;
      unsigned lo = f2bf(sx * inm), hi = f2bf(sy * inm);
      ((unsigned*)(mn + (size_t)jc * DD))[tid] = lo | (hi << 16);
    }
    // per-row norms: one 16-lane group per row
    {
      const int g = tid >> 4, l16 = tid & 15;
      float nx2 = 0.f, dxs = 0.f, t2 = 0.f;
      const float2* xr2 = (const float2*)(xb + g * LDX);
      const float2* sm2 = (const float2*)sums;
#pragma unroll
      for (int t = 0; t < 16; ++t) {
        float2 xv = xr2[l16 + t * 16];
        float2 sc = sm2[l16 + t * 16];
        nx2 = fmaf(xv.x, xv.x, fmaf(xv.y, xv.y, nx2));
        dxs = fmaf(xv.x, sc.x, fmaf(xv.y, sc.y, dxs));
        float tx = sc.x - xv.x, ty = sc.y - xv.y;
        t2 = fmaf(tx, tx, fmaf(ty, ty, t2));
      }
#pragma unroll
      for (int off = 1; off < 16; off <<= 1) {
        nx2 += __shfl_xor(nx2, off, 64);
        dxs += __shfl_xor(dxs, off, 64);
        t2  += __shfl_xor(t2,  off, 64);
      }
      if (l16 == 0) {
        float nxv = sqrtf(nx2);
        float tn  = sqrtf(t2);
        float num = (dxs - nx2) * (1.0f / (SS - 1));
        float den = fmaxf(nxv * tn * (1.0f / (SS - 1)), EPSV);
        rinv[g] = 1.0f / nxv;
        float spv = num / den;
        spos[g] = spv;
        if (cb == 0) simpos[jc * SS + g] = spv;
      }
    }
    __syncthreads();
    // A-fragment extraction: the owning wave packs rows of class jc
    if (wid == (r >> 1)) {
      const int rt = r & 1;
      const float ri = rinv[cL];
#pragma unroll
      for (int kc = 0; kc < 16; ++kc) {
        const float* s = xb + cL * LDX + kc * 32 + quad * 8;
        const float4 a = *(const float4*)s;
        const float4 b2 = *(const float4*)(s + 4);
        short8 v;
        v[0] = f2bf(a.x * ri); v[1] = f2bf(a.y * ri);
        v[2] = f2bf(a.z * ri); v[3] = f2bf(a.w * ri);
        v[4] = f2bf(b2.x * ri); v[5] = f2bf(b2.y * ri);
        v[6] = f2bf(b2.z * ri); v[7] = f2bf(b2.w * ri);
        af[rt][kc] = v;
      }
#pragma unroll
      for (int r4 = 0; r4 < 4; ++r4) sp[rt][r4] = spos[quad * 4 + r4];
    }
    __syncthreads();   // protect xb from next round's stage
  }

  // ---- device-scope grid barrier (all 256 blocks resident) ----
  if (tid == 0) {
    __builtin_amdgcn_fence(__ATOMIC_RELEASE, "agent");
    __hip_atomic_fetch_add(cnt, 1u, __ATOMIC_RELAXED, __HIP_MEMORY_SCOPE_AGENT);
    while (__hip_atomic_load(cnt, __ATOMIC_RELAXED, __HIP_MEMORY_SCOPE_AGENT) <
           (unsigned)gridDim.x)
      __builtin_amdgcn_s_sleep(8);
    __builtin_amdgcn_fence(__ATOMIC_ACQUIRE, "agent");
  }
  __syncthreads();

  // ---- phase 2: MFMA GEMM + fused exp-sum (R7 loop, 256 threads) ----
  ushort_t (*bs)[CHUNK * LDB] = (ushort_t(*)[CHUNK * LDB])smem;  // 66560 B

  // stage chunk 0: 32 B-rows; each wave stages one row per iter
  {
    const ushort_t* gsrc = mn + (size_t)cbase * DD;
#pragma unroll
    for (int t = 0; t < 8; ++t) {
      const int rr = wid + t * 4;
      async16(&bs[0][rr * LDB + lane * 8], gsrc + (size_t)rr * DD + lane * 8);
    }
  }

#pragma unroll
  for (int cc = 0; cc < NCHUNK; ++cc) {
    if (cc < NCHUNK - 1) {
      const ushort_t* gsrc = mn + (size_t)(cbase + (cc + 1) * CHUNK) * DD;
      ushort_t* dst = bs[(cc + 1) & 1];
#pragma unroll
      for (int t = 0; t < 8; ++t) {
        const int rr = wid + t * 4;
        async16(&dst[rr * LDB + lane * 8], gsrc + (size_t)rr * DD + lane * 8);
      }
      SCHED0();
      asm volatile("s_waitcnt vmcnt(8)" ::: "memory");
    } else {
      asm volatile("s_waitcnt vmcnt(0)" ::: "memory");
    }
    SCHED0();
    SBAR();   // all waves' chunk-cc loads landed
    SCHED0();

    const ushort_t* B = bs[cc & 1];
    f32x4 acc[2][2];
#pragma unroll
    for (int rt = 0; rt < 2; ++rt)
#pragma unroll
      for (int f = 0; f < 2; ++f) acc[rt][f] = (f32x4){0.f, 0.f, 0.f, 0.f};
#pragma unroll
    for (int kc = 0; kc < 16; ++kc) {
      short8 bfr[2];
#pragma unroll
      for (int f = 0; f < 2; ++f)
        bfr[f] = *(const short8*)&B[(f * 16 + cL) * LDB + kc * 32 + quad * 8];
#pragma unroll
      for (int rt = 0; rt < 2; ++rt)
#pragma unroll
        for (int f = 0; f < 2; ++f)
          acc[rt][f] = __builtin_amdgcn_mfma_f32_16x16x32_bf16(
              af[rt][kc], bfr[f], acc[rt][f], 0, 0, 0);
    }
    const int c0 = cbase + cc * CHUNK;
#pragma unroll
    for (int rt = 0; rt < 2; ++rt)
#pragma unroll
      for (int f = 0; f < 2; ++f) {
        const int cg = c0 + f * 16 + cL;
        const bool diag = (cg == jw[rt]);
#pragma unroll
        for (int r4 = 0; r4 < 4; ++r4) {
          const float sim = diag ? sp[rt][r4] : acc[rt][f][r4];
          sacc[rt][r4] += __expf(fmaf(wp, sim, bv));
        }
      }
    if (cc < NCHUNK - 1) {
      SCHED0();
      SBAR();   // all waves done reading bs[cc&1]
      SCHED0();
    }
  }

#pragma unroll
  for (int rt = 0; rt < 2; ++rt)
#pragma unroll
    for (int r4 = 0; r4 < 4; ++r4) {
      float v = sacc[rt][r4];
#pragma unroll
      for (int off = 1; off < 16; off <<= 1) v += __shfl_xor(v, off, 64);
      if (cL == 0)
        ps[(size_t)(row0w + rt * 16 + quad * 4 + r4) * 2 + cb] = v;
    }
}

// ---------------- tail: per-row loss + parallel reduce ----------------
__global__ __launch_bounds__(256) void k_combine(
    const float* __restrict__ ps, const float* __restrict__ simpos,
    const float* __restrict__ wptr, const float* __restrict__ bptr,
    float* __restrict__ p2) {
  __shared__ float red[4];
  const int tid = threadIdx.x;
  const int row = blockIdx.x * 256 + tid;
  const float wp = softplusf(wptr[0]), bv = bptr[0];
  const float2 v2 = ((const float2*)ps)[row];
  float v = logf(v2.x + v2.y) - fmaf(wp, simpos[row], bv);
#pragma unroll
  for (int off = 32; off > 0; off >>= 1) v += __shfl_xor(v, off, 64);
  if ((tid & 63) == 0) red[tid >> 6] = v;
  __syncthreads();
  if (tid == 0) p2[blockIdx.x] = red[0] + red[1] + red[2] + red[3];
}

__global__ __launch_bounds__(64) void k_fin(const float* __restrict__ p2,
                                            float* __restrict__ out) {
  const int tid = threadIdx.x;
  float v = p2[tid];
#pragma unroll
  for (int off = 32; off > 0; off >>= 1) v += __shfl_xor(v, off, 64);
  if (tid == 0) out[0] = v * (1.0f / RR);
}

extern "C" void kernel_launch(void* const* d_in, const int* in_sizes, int n_in,
                              void* d_out, int out_size, void* d_ws, size_t ws_size,
                              hipStream_t stream) {
  const float* x = (const float*)d_in[0];
  const float* w = (const float*)d_in[1];
  const float* b = (const float*)d_in[2];
  float* out = (float*)d_out;

  char* base = (char*)d_ws;
  unsigned* cnt = (unsigned*)base;                 // 4 B, zeroed each launch
  char* pp = base + 256;
  ushort_t* mn = (ushort_t*)pp;  pp += (size_t)CC * DD * 2;   // 1 MB
  float* simpos = (float*)pp;    pp += (size_t)RR * 4;        // 64 KB
  float* ps     = (float*)pp;    pp += (size_t)RR * 2 * 4;    // 128 KB
  float* p2     = (float*)pp;                                 // 256 B

  hipMemsetAsync(cnt, 0, 4, stream);
  k_fused<<<256, 256, 0, stream>>>(x, mn, simpos, w, b, ps, cnt);
  k_combine<<<RR / 256, 256, 0, stream>>>(ps, simpos, w, b, p2);
  k_fin<<<1, 64, 0, stream>>>(p2, out);
}